// Round 1
// baseline (476.100 us; speedup 1.0000x reference)
//
#include <hip/hip_runtime.h>

#define DEVINL __device__ __forceinline__

constexpr int BB = 256;   // batch
constexpr int TT = 512;   // time steps
constexpr int FF = 128;   // features
constexpr int HH = 128;   // hidden size
constexpr float S2F = 0.70710678118654752440f;

// ---- DPP cross-lane helpers (all-lanes-active call sites only) ----
template<int CTRL>
DEVINL float dppf(float x) {
  return __builtin_bit_cast(float,
    __builtin_amdgcn_update_dpp(0, __builtin_bit_cast(int, x), CTRL, 0xF, 0xF, true));
}

// allreduce within each 16-lane row: xor1, xor2, then mirror patterns
// (row_half_mirror == xor4 once quads are uniform; row_mirror == xor8 once
//  8-groups are uniform)
DEVINL float red16(float v) {
  v += dppf<0xB1>(v);    // quad_perm [1,0,3,2]  == xor 1
  v += dppf<0x4E>(v);    // quad_perm [2,3,0,1]  == xor 2
  v += dppf<0x141>(v);   // row_half_mirror      (== xor 4 here)
  v += dppf<0x140>(v);   // row_mirror           (== xor 8 here)
  return v;
}

DEVINL float red64(float v) {
  v = red16(v);
  v += __shfl_xor(v, 16, 64);
  v += __shfl_xor(v, 32, 64);
  return v;
}

DEVINL float rcp_f (float x){ return __builtin_amdgcn_rcpf(x); }
DEVINL float rsq_f (float x){ return __builtin_amdgcn_rsqf(x); }
DEVINL float sqrt_f(float x){ return __builtin_amdgcn_sqrtf(x); }

DEVINL float sigf(float x){ return rcp_f(1.f + __expf(-x)); }
DEVINL float tanh_f(float x){
  float a = __expf(-2.f * fabsf(x));
  float t = (1.f - a) * rcp_f(1.f + a);
  return copysignf(t, x);
}

// ============================================================
// Kernel 1: y_x[r][q] = sum_f x[r][f] * Win_w[q][128+f] + Win_b[q]
// one wave per row, float2 per lane, DPP allreduce. rows = B*T.
// ============================================================
__global__ __launch_bounds__(64)
void yx_pre(const float* __restrict__ x,
            const float* __restrict__ Win_w,
            const float* __restrict__ Win_b,
            float* __restrict__ yx, int rowsPerBlk)
{
  const int lane = threadIdx.x;
  const float wx0a = Win_w[0*256 + 128 + 2*lane], wx0b = Win_w[0*256 + 129 + 2*lane];
  const float wx1a = Win_w[1*256 + 128 + 2*lane], wx1b = Win_w[1*256 + 129 + 2*lane];
  const float wx2a = Win_w[2*256 + 128 + 2*lane], wx2b = Win_w[2*256 + 129 + 2*lane];
  const float wx3a = Win_w[3*256 + 128 + 2*lane], wx3b = Win_w[3*256 + 129 + 2*lane];
  const float bb0 = Win_b[0], bb1 = Win_b[1], bb2 = Win_b[2], bb3 = Win_b[3];

  const int r0 = blockIdx.x * rowsPerBlk;
  float2 xv = *reinterpret_cast<const float2*>(x + (size_t)r0 * FF + 2*lane);
  for (int k = 0; k < rowsPerBlk; ++k) {
    const int r = r0 + k;
    float2 cur = xv;
    if (k + 1 < rowsPerBlk)
      xv = *reinterpret_cast<const float2*>(x + (size_t)(r + 1) * FF + 2*lane);
    float p0 = fmaf(cur.x, wx0a, cur.y * wx0b);
    float p1 = fmaf(cur.x, wx1a, cur.y * wx1b);
    float p2 = fmaf(cur.x, wx2a, cur.y * wx2b);
    float p3 = fmaf(cur.x, wx3a, cur.y * wx3b);
    p0 = red64(p0); p1 = red64(p1); p2 = red64(p2); p3 = red64(p3);
    if (lane == 0)
      reinterpret_cast<float4*>(yx)[r] = make_float4(p0 + bb0, p1 + bb1, p2 + bb2, p3 + bb3);
  }
}

// ============================================================
// Kernel 2: the recurrent scan. One wave per batch element.
// lane = grp*16 + ai ; grp in {forget,input,update,output} ; ai = amplitude.
// Each lane also owns hidden units j = lane and j = lane+64.
// ============================================================
__global__ __launch_bounds__(64)
void qlstm_rec(const float* __restrict__ Win_w,
               const float* __restrict__ Wout_w,
               const float* __restrict__ Wout_b,
               const float* __restrict__ w_f,
               const float* __restrict__ w_i,
               const float* __restrict__ w_u,
               const float* __restrict__ w_o,
               const float* __restrict__ yx,
               float* __restrict__ out)
{
  const int lane = threadIdx.x;
  const int grp  = lane >> 4;
  const int ai   = lane & 15;
  const int b    = blockIdx.x;

  // recurrent weights Wh[q][j] (j = 0..127 part of Win_w rows)
  float whA[4], whB[4];
  #pragma unroll
  for (int q = 0; q < 4; ++q) {
    whA[q] = Win_w[q*256 + lane];
    whB[q] = Win_w[q*256 + 64 + lane];
  }
  const float4 woA = reinterpret_cast<const float4*>(Wout_w)[lane];
  const float4 woB = reinterpret_cast<const float4*>(Wout_w)[lane + 64];
  const float  wbA = Wout_b[lane], wbB = Wout_b[lane + 64];

  // ring RY weights for this lane's gate group (half-angle cos/sin, fixed)
  const float* wr = (grp == 0) ? w_f : (grp == 1) ? w_i : (grp == 2) ? w_u : w_o;
  float cw[4], sw[4];
  #pragma unroll
  for (int q = 0; q < 4; ++q) {
    float t = 0.5f * wr[q];
    cw[q] = cosf(t);
    sw[q] = sinf(t);
  }

  // amplitude-index bits (qubit0 = MSB) and CNOT-ring-permuted Z signs:
  // CNOT(0,1),(1,2),(2,3),(3,0) maps basis k -> f(k); fold into signs.
  const int b0 = (ai >> 3) & 1, b1 = (ai >> 2) & 1, b2 = (ai >> 1) & 1, b3 = ai & 1;
  const int c1 = b1 ^ b0, c2 = b2 ^ c1, c3 = b3 ^ c2, c0 = b0 ^ c3;
  const float sz0 = 1.f - 2.f*(float)c0, sz1 = 1.f - 2.f*(float)c1;
  const float sz2 = 1.f - 2.f*(float)c2, sz3 = 1.f - 2.f*(float)c3;

  float h0 = 0.f, h1 = 0.f, cc0 = 0.f, cc1 = 0.f;

  __shared__ float Elds[16];

  const float4* yxb = reinterpret_cast<const float4*>(yx) + (size_t)b * TT;
  float4 yn = yxb[0];

  float* outseq = out + (size_t)b * TT * HH;

  for (int t = 0; t < TT; ++t) {
    const float4 yc = yn;
    if (t + 1 < TT) yn = yxb[t + 1];

    // ---- y = Wh @ h + y_x ----
    float r0 = h0*whA[0] + h1*whB[0];
    float r1 = h0*whA[1] + h1*whB[1];
    float r2 = h0*whA[2] + h1*whB[2];
    float r3 = h0*whA[3] + h1*whB[3];
    r0 = red64(r0); r1 = red64(r1); r2 = red64(r2); r3 = red64(r3);
    const float ys[4] = { r0 + yc.x, r1 + yc.y, r2 + yc.z, r3 + yc.w };

    // ---- per-qubit 2-vectors u_q = RY(w)·RZ(atan(y^2))·RY(atan(y))·H |0>
    //      using half-angle-of-arctan closed forms (no atan/sincos) ----
    float ure[4][2], uim[4][2];
    #pragma unroll
    for (int q = 0; q < 4; ++q) {
      const float y   = ys[q];
      const float r   = rsq_f(fmaf(y, y, 1.f));          // cos(atan y)
      const float ca  = sqrt_f(0.5f * (1.f + r));        // cos(a/2)
      const float sa  = ca * (y * r) * rcp_f(1.f + r);   // sin(a/2), stable
      const float yq  = y * y;
      const float rr  = rsq_f(fmaf(yq, yq, 1.f));        // cos(atan y^2)
      const float cb  = sqrt_f(0.5f * (1.f + rr));       // cos(b/2)
      const float sb  = cb * (yq * rr) * rcp_f(1.f + rr);// sin(b/2) >= 0
      const float m0  = S2F * (ca - sa), m1 = S2F * (ca + sa);
      const float v0re = m0 * cb, v0im = -m0 * sb;
      const float v1re = m1 * cb, v1im =  m1 * sb;
      ure[q][0] = cw[q]*v0re - sw[q]*v1re;  uim[q][0] = cw[q]*v0im - sw[q]*v1im;
      ure[q][1] = sw[q]*v0re + cw[q]*v1re;  uim[q][1] = sw[q]*v0im + cw[q]*v1im;
    }

    // ---- amplitude = product of selected components (pre-CNOT state) ----
    float are = b0 ? ure[0][1] : ure[0][0], aim = b0 ? uim[0][1] : uim[0][0];
    float bre = b1 ? ure[1][1] : ure[1][0], bim = b1 ? uim[1][1] : uim[1][0];
    float t0re = are*bre - aim*bim, t0im = are*bim + aim*bre;
    float cre = b2 ? ure[2][1] : ure[2][0], cim = b2 ? uim[2][1] : uim[2][0];
    float t1re = t0re*cre - t0im*cim, t1im = t0re*cim + t0im*cre;
    float dre = b3 ? ure[3][1] : ure[3][0], dim = b3 ? uim[3][1] : uim[3][0];
    float fre = t1re*dre - t1im*dim, fim = t1re*dim + t1im*dre;

    // ---- probs + CNOT-permuted PauliZ expvals, 16-lane reduce ----
    const float p  = fre*fre + fim*fim;
    const float e0 = red16(p * sz0);
    const float e1 = red16(p * sz1);
    const float e2 = red16(p * sz2);
    const float e3 = red16(p * sz3);

    // ---- share 4x4 expval matrix across gate groups (single wave: no barrier) ----
    if (ai == 0)
      reinterpret_cast<float4*>(Elds)[grp] = make_float4(e0, e1, e2, e3);
    const float4 Ef = reinterpret_cast<float4*>(Elds)[0];
    const float4 Ei = reinterpret_cast<float4*>(Elds)[1];
    const float4 Eu = reinterpret_cast<float4*>(Elds)[2];
    const float4 Eo = reinterpret_cast<float4*>(Elds)[3];

    // ---- gate projections + LSTM update for j = lane and j = lane+64 ----
    const float zf0 = fmaf(Ef.x, woA.x, fmaf(Ef.y, woA.y, fmaf(Ef.z, woA.z, fmaf(Ef.w, woA.w, wbA))));
    const float zi0 = fmaf(Ei.x, woA.x, fmaf(Ei.y, woA.y, fmaf(Ei.z, woA.z, fmaf(Ei.w, woA.w, wbA))));
    const float zu0 = fmaf(Eu.x, woA.x, fmaf(Eu.y, woA.y, fmaf(Eu.z, woA.z, fmaf(Eu.w, woA.w, wbA))));
    const float zo0 = fmaf(Eo.x, woA.x, fmaf(Eo.y, woA.y, fmaf(Eo.z, woA.z, fmaf(Eo.w, woA.w, wbA))));
    const float zf1 = fmaf(Ef.x, woB.x, fmaf(Ef.y, woB.y, fmaf(Ef.z, woB.z, fmaf(Ef.w, woB.w, wbB))));
    const float zi1 = fmaf(Ei.x, woB.x, fmaf(Ei.y, woB.y, fmaf(Ei.z, woB.z, fmaf(Ei.w, woB.w, wbB))));
    const float zu1 = fmaf(Eu.x, woB.x, fmaf(Eu.y, woB.y, fmaf(Eu.z, woB.z, fmaf(Eu.w, woB.w, wbB))));
    const float zo1 = fmaf(Eo.x, woB.x, fmaf(Eo.y, woB.y, fmaf(Eo.z, woB.z, fmaf(Eo.w, woB.w, wbB))));

    const float f0 = sigf(zf0), i0 = sigf(zi0), g0 = tanh_f(zu0), o0 = sigf(zo0);
    const float f1 = sigf(zf1), i1 = sigf(zi1), g1 = tanh_f(zu1), o1 = sigf(zo1);

    cc0 = f0*cc0 + i0*g0;   h0 = o0 * tanh_f(cc0);
    cc1 = f1*cc1 + i1*g1;   h1 = o1 * tanh_f(cc1);

    outseq[(size_t)t*HH + lane]      = h0;
    outseq[(size_t)t*HH + 64 + lane] = h1;
  }

  const size_t hoff = (size_t)BB * TT * HH;
  out[hoff + (size_t)b*HH + lane]      = h0;
  out[hoff + (size_t)b*HH + 64 + lane] = h1;
  const size_t coff = hoff + (size_t)BB * HH;
  out[coff + (size_t)b*HH + lane]      = cc0;
  out[coff + (size_t)b*HH + 64 + lane] = cc1;
}

extern "C" void kernel_launch(void* const* d_in, const int* in_sizes, int n_in,
                              void* d_out, int out_size, void* d_ws, size_t ws_size,
                              hipStream_t stream) {
  const float* x      = (const float*)d_in[0];
  const float* Win_w  = (const float*)d_in[1];
  const float* Win_b  = (const float*)d_in[2];
  const float* Wout_w = (const float*)d_in[3];
  const float* Wout_b = (const float*)d_in[4];
  const float* w_f    = (const float*)d_in[5];
  const float* w_i    = (const float*)d_in[6];
  const float* w_u    = (const float*)d_in[7];
  const float* w_o    = (const float*)d_in[8];
  float* out = (float*)d_out;
  float* yx  = (float*)d_ws;   // B*T*4 floats = 2 MB scratch

  const int rows = BB * TT;          // 131072
  const int rowsPerBlk = 64;
  yx_pre<<<rows / rowsPerBlk, 64, 0, stream>>>(x, Win_w, Win_b, yx, rowsPerBlk);
  qlstm_rec<<<BB, 64, 0, stream>>>(Win_w, Wout_w, Wout_b, w_f, w_i, w_u, w_o, yx, out);
}

// Round 2
// 311.897 us; speedup vs baseline: 1.5265x; 1.5265x over previous
//
#include <hip/hip_runtime.h>

#define DEVINL __device__ __forceinline__

constexpr int BB = 256;   // batch
constexpr int TT = 512;   // time steps
constexpr int FF = 128;   // features
constexpr int HH = 128;   // hidden size

// ---- DPP cross-lane helpers (all-lanes-active call sites only) ----
template<int CTRL>
DEVINL float dppf(float x) {
  return __builtin_bit_cast(float,
    __builtin_amdgcn_update_dpp(0, __builtin_bit_cast(int, x), CTRL, 0xF, 0xF, true));
}

// allreduce within each 16-lane row (values end uniform per row)
DEVINL float red16(float v) {
  v += dppf<0xB1>(v);    // quad_perm [1,0,3,2]  == xor 1
  v += dppf<0x4E>(v);    // quad_perm [2,3,0,1]  == xor 2
  v += dppf<0x141>(v);   // row_half_mirror      (== xor 4 here)
  v += dppf<0x140>(v);   // row_mirror           (== xor 8 here)
  return v;
}

// cross-row sums via gfx950 permlane swaps (VALU, no DS / lgkmcnt).
// After red16, rows are internally uniform; pairing rows 0<->1, 2<->3 then
// halves 0-31 <-> 32-63 yields the full 64-lane sum in every lane.
DEVINL float swap16add(float v) {
  float a = v, b = v;
  asm("s_nop 0\n\tv_permlane16_swap_b32 %0, %1" : "+v"(a), "+v"(b));
  return a + b;
}
DEVINL float swap32add(float v) {
  float a = v, b = v;
  asm("s_nop 0\n\tv_permlane32_swap_b32 %0, %1" : "+v"(a), "+v"(b));
  return a + b;
}
DEVINL float red64(float v) { return swap32add(swap16add(red16(v))); }

DEVINL float rcp_f(float x){ return __builtin_amdgcn_rcpf(x); }
DEVINL float rsq_f(float x){ return __builtin_amdgcn_rsqf(x); }

DEVINL float sigf(float x){ return rcp_f(1.f + __expf(-x)); }
DEVINL float tanh_f(float x){
  float a = __expf(-2.f * fabsf(x));
  float t = (1.f - a) * rcp_f(1.f + a);
  return copysignf(t, x);
}

// ============================================================
// Kernel 1: y_x[r][q] = sum_f x[r][f] * Win_w[q][128+f] + Win_b[q]
// one wave per row, float2 per lane, DPP+permlane allreduce. rows = B*T.
// ============================================================
__global__ __launch_bounds__(64)
void yx_pre(const float* __restrict__ x,
            const float* __restrict__ Win_w,
            const float* __restrict__ Win_b,
            float* __restrict__ yx, int rowsPerBlk)
{
  const int lane = threadIdx.x;
  const float wx0a = Win_w[0*256 + 128 + 2*lane], wx0b = Win_w[0*256 + 129 + 2*lane];
  const float wx1a = Win_w[1*256 + 128 + 2*lane], wx1b = Win_w[1*256 + 129 + 2*lane];
  const float wx2a = Win_w[2*256 + 128 + 2*lane], wx2b = Win_w[2*256 + 129 + 2*lane];
  const float wx3a = Win_w[3*256 + 128 + 2*lane], wx3b = Win_w[3*256 + 129 + 2*lane];
  const float bb0 = Win_b[0], bb1 = Win_b[1], bb2 = Win_b[2], bb3 = Win_b[3];

  const int r0 = blockIdx.x * rowsPerBlk;
  float2 xv = *reinterpret_cast<const float2*>(x + (size_t)r0 * FF + 2*lane);
  for (int k = 0; k < rowsPerBlk; ++k) {
    const int r = r0 + k;
    float2 cur = xv;
    if (k + 1 < rowsPerBlk)
      xv = *reinterpret_cast<const float2*>(x + (size_t)(r + 1) * FF + 2*lane);
    float p0 = fmaf(cur.x, wx0a, cur.y * wx0b);
    float p1 = fmaf(cur.x, wx1a, cur.y * wx1b);
    float p2 = fmaf(cur.x, wx2a, cur.y * wx2b);
    float p3 = fmaf(cur.x, wx3a, cur.y * wx3b);
    p0 = red64(p0); p1 = red64(p1); p2 = red64(p2); p3 = red64(p3);
    if (lane == 0)
      reinterpret_cast<float4*>(yx)[r] = make_float4(p0 + bb0, p1 + bb1, p2 + bb2, p3 + bb3);
  }
}

// ============================================================
// Kernel 2: the recurrent scan. One wave per batch element.
// The VQC is collapsed analytically: the pre-CNOT state is a product
// state, so with r=1/sqrt(1+y^2), rr=1/sqrt(1+y^4):
//   d_q = E[(-1)^{b_q}] = -r*(y*cos(w_q) + rr*sin(w_q))
// and the CNOT-ring-permuted PauliZ expvals factorize by independence:
//   E0 = d1*d2*d3, E1 = d0*d1, E2 = d0*d1*d2, E3 = d0*d1*d2*d3.
// No amplitudes, no 16-lane reduction, no LDS, no DS ops at all.
// Each lane owns hidden units j = 2*lane, 2*lane+1.
// ============================================================
__global__ __launch_bounds__(64)
void qlstm_rec(const float* __restrict__ Win_w,
               const float* __restrict__ Wout_w,
               const float* __restrict__ Wout_b,
               const float* __restrict__ w_f,
               const float* __restrict__ w_i,
               const float* __restrict__ w_u,
               const float* __restrict__ w_o,
               const float* __restrict__ yx,
               float* __restrict__ out)
{
  const int lane = threadIdx.x;
  const int b    = blockIdx.x;
  const int j0   = 2*lane, j1 = 2*lane + 1;

  // recurrent weights Wh[q][j] (h-part of Win_w rows)
  float whA[4], whB[4];
  #pragma unroll
  for (int q = 0; q < 4; ++q) {
    whA[q] = Win_w[q*256 + j0];
    whB[q] = Win_w[q*256 + j1];
  }
  const float4 woA = reinterpret_cast<const float4*>(Wout_w)[j0];
  const float4 woB = reinterpret_cast<const float4*>(Wout_w)[j1];
  const float  wbA = Wout_b[j0], wbB = Wout_b[j1];

  // ring RY weights: full-angle -cos / -sin, all gates, every lane (uniform)
  float ncw[4][4], nsw[4][4];
  const float* ws[4] = { w_f, w_i, w_u, w_o };
  #pragma unroll
  for (int g = 0; g < 4; ++g) {
    #pragma unroll
    for (int q = 0; q < 4; ++q) {
      const float w = ws[g][q];
      ncw[g][q] = -cosf(w);
      nsw[g][q] = -sinf(w);
    }
  }

  float h0 = 0.f, h1 = 0.f, cc0 = 0.f, cc1 = 0.f;

  const float4* yxb = reinterpret_cast<const float4*>(yx) + (size_t)b * TT;
  float4 yn = yxb[0];

  float* outseq = out + (size_t)b * TT * HH;

  for (int t = 0; t < TT; ++t) {
    const float4 yc = yn;
    if (t + 1 < TT) yn = yxb[t + 1];

    // ---- y = Wh @ h + y_x  (only cross-lane stage; DPP+permlane) ----
    float r0 = fmaf(h0, whA[0], h1 * whB[0]);
    float r1 = fmaf(h0, whA[1], h1 * whB[1]);
    float r2 = fmaf(h0, whA[2], h1 * whB[2]);
    float r3 = fmaf(h0, whA[3], h1 * whB[3]);
    r0 = red64(r0); r1 = red64(r1); r2 = red64(r2); r3 = red64(r3);
    const float ys[4] = { r0 + yc.x, r1 + yc.y, r2 + yc.z, r3 + yc.w };

    // ---- per-qubit A = y*r, B = r*rr (2 rsq each, uniform) ----
    float Aq[4], Bq[4];
    #pragma unroll
    for (int q = 0; q < 4; ++q) {
      const float y  = ys[q];
      const float y2 = y * y;
      const float r  = rsq_f(y2 + 1.f);
      const float rr = rsq_f(fmaf(y2, y2, 1.f));
      Aq[q] = y * r;
      Bq[q] = r * rr;
    }

    // ---- per-gate d_q and ring-permuted expvals ----
    float4 E[4];
    #pragma unroll
    for (int g = 0; g < 4; ++g) {
      const float d0 = fmaf(ncw[g][0], Aq[0], nsw[g][0] * Bq[0]);
      const float d1 = fmaf(ncw[g][1], Aq[1], nsw[g][1] * Bq[1]);
      const float d2 = fmaf(ncw[g][2], Aq[2], nsw[g][2] * Bq[2]);
      const float d3 = fmaf(ncw[g][3], Aq[3], nsw[g][3] * Bq[3]);
      const float e1 = d0 * d1;
      const float e2 = e1 * d2;
      E[g] = make_float4(d1 * d2 * d3, e1, e2, e2 * d3);
    }

    // ---- gate projections + LSTM update for j0, j1 ----
    float z0[4], z1[4];
    #pragma unroll
    for (int g = 0; g < 4; ++g) {
      z0[g] = fmaf(E[g].x, woA.x, fmaf(E[g].y, woA.y, fmaf(E[g].z, woA.z, fmaf(E[g].w, woA.w, wbA))));
      z1[g] = fmaf(E[g].x, woB.x, fmaf(E[g].y, woB.y, fmaf(E[g].z, woB.z, fmaf(E[g].w, woB.w, wbB))));
    }

    const float f0 = sigf(z0[0]), i0 = sigf(z0[1]), g0 = tanh_f(z0[2]), o0 = sigf(z0[3]);
    const float f1 = sigf(z1[0]), i1 = sigf(z1[1]), g1 = tanh_f(z1[2]), o1 = sigf(z1[3]);

    cc0 = fmaf(f0, cc0, i0 * g0);   h0 = o0 * tanh_f(cc0);
    cc1 = fmaf(f1, cc1, i1 * g1);   h1 = o1 * tanh_f(cc1);

    *reinterpret_cast<float2*>(outseq + (size_t)t * HH + j0) = make_float2(h0, h1);
  }

  const size_t hoff = (size_t)BB * TT * HH;
  *reinterpret_cast<float2*>(out + hoff + (size_t)b * HH + j0) = make_float2(h0, h1);
  const size_t coff = hoff + (size_t)BB * HH;
  *reinterpret_cast<float2*>(out + coff + (size_t)b * HH + j0) = make_float2(cc0, cc1);
}

extern "C" void kernel_launch(void* const* d_in, const int* in_sizes, int n_in,
                              void* d_out, int out_size, void* d_ws, size_t ws_size,
                              hipStream_t stream) {
  const float* x      = (const float*)d_in[0];
  const float* Win_w  = (const float*)d_in[1];
  const float* Win_b  = (const float*)d_in[2];
  const float* Wout_w = (const float*)d_in[3];
  const float* Wout_b = (const float*)d_in[4];
  const float* w_f    = (const float*)d_in[5];
  const float* w_i    = (const float*)d_in[6];
  const float* w_u    = (const float*)d_in[7];
  const float* w_o    = (const float*)d_in[8];
  float* out = (float*)d_out;
  float* yx  = (float*)d_ws;   // B*T*4 floats = 2 MB scratch

  const int rows = BB * TT;          // 131072
  const int rowsPerBlk = 64;
  yx_pre<<<rows / rowsPerBlk, 64, 0, stream>>>(x, Win_w, Win_b, yx, rowsPerBlk);
  qlstm_rec<<<BB, 64, 0, stream>>>(Win_w, Wout_w, Wout_b, w_f, w_i, w_u, w_o, yx, out);
}

// Round 3
// 275.686 us; speedup vs baseline: 1.7270x; 1.1313x over previous
//
#include <hip/hip_runtime.h>

#define DEVINL __device__ __forceinline__

constexpr int BB = 256;   // batch
constexpr int TT = 512;   // time steps
constexpr int FF = 128;   // features
constexpr int HH = 128;   // hidden size

typedef float f2 __attribute__((ext_vector_type(2)));

DEVINL f2 pkfma(f2 a, f2 b, f2 c) { return __builtin_elementwise_fma(a, b, c); }
DEVINL f2 splat(float s) { return (f2){s, s}; }

// ---- DPP cross-lane helpers (all-lanes-active call sites only) ----
template<int CTRL>
DEVINL float dppf(float x) {
  return __builtin_bit_cast(float,
    __builtin_amdgcn_update_dpp(0, __builtin_bit_cast(int, x), CTRL, 0xF, 0xF, true));
}

// allreduce within each 16-lane row (values end uniform per row)
DEVINL float red16(float v) {
  v += dppf<0xB1>(v);    // quad_perm [1,0,3,2]  == xor 1
  v += dppf<0x4E>(v);    // quad_perm [2,3,0,1]  == xor 2
  v += dppf<0x141>(v);   // row_half_mirror      (== xor 4 here)
  v += dppf<0x140>(v);   // row_mirror           (== xor 8 here)
  return v;
}

// cross-row sums via gfx950 permlane swaps (VALU, no DS / lgkmcnt).
DEVINL float swap16add(float v) {
  float a = v, b = v;
  asm("s_nop 0\n\tv_permlane16_swap_b32 %0, %1" : "+v"(a), "+v"(b));
  return a + b;
}
DEVINL float swap32add(float v) {
  float a = v, b = v;
  asm("s_nop 0\n\tv_permlane32_swap_b32 %0, %1" : "+v"(a), "+v"(b));
  return a + b;
}
DEVINL float red64(float v) { return swap32add(swap16add(red16(v))); }

DEVINL float rcp_f(float x){ return __builtin_amdgcn_rcpf(x); }
DEVINL float rsq_f(float x){ return __builtin_amdgcn_rsqf(x); }
DEVINL float ex2_f(float x){ return __builtin_amdgcn_exp2f(x); }

// ============================================================
// Kernel 1: y_x[r][q] = sum_f x[r][f] * Win_w[q][128+f] + Win_b[q]
// ============================================================
__global__ __launch_bounds__(64)
void yx_pre(const float* __restrict__ x,
            const float* __restrict__ Win_w,
            const float* __restrict__ Win_b,
            float* __restrict__ yx, int rowsPerBlk)
{
  const int lane = threadIdx.x;
  const float wx0a = Win_w[0*256 + 128 + 2*lane], wx0b = Win_w[0*256 + 129 + 2*lane];
  const float wx1a = Win_w[1*256 + 128 + 2*lane], wx1b = Win_w[1*256 + 129 + 2*lane];
  const float wx2a = Win_w[2*256 + 128 + 2*lane], wx2b = Win_w[2*256 + 129 + 2*lane];
  const float wx3a = Win_w[3*256 + 128 + 2*lane], wx3b = Win_w[3*256 + 129 + 2*lane];
  const float bb0 = Win_b[0], bb1 = Win_b[1], bb2 = Win_b[2], bb3 = Win_b[3];

  const int r0 = blockIdx.x * rowsPerBlk;
  float2 xv = *reinterpret_cast<const float2*>(x + (size_t)r0 * FF + 2*lane);
  for (int k = 0; k < rowsPerBlk; ++k) {
    const int r = r0 + k;
    float2 cur = xv;
    if (k + 1 < rowsPerBlk)
      xv = *reinterpret_cast<const float2*>(x + (size_t)(r + 1) * FF + 2*lane);
    float p0 = fmaf(cur.x, wx0a, cur.y * wx0b);
    float p1 = fmaf(cur.x, wx1a, cur.y * wx1b);
    float p2 = fmaf(cur.x, wx2a, cur.y * wx2b);
    float p3 = fmaf(cur.x, wx3a, cur.y * wx3b);
    p0 = red64(p0); p1 = red64(p1); p2 = red64(p2); p3 = red64(p3);
    if (lane == 0)
      reinterpret_cast<float4*>(yx)[r] = make_float4(p0 + bb0, p1 + bb1, p2 + bb2, p3 + bb3);
  }
}

// ============================================================
// Kernel 2: recurrent scan, one wave per batch element.
// Analytic VQC: d_q = -r*(y*cos w_q + rr*sin w_q); ring-permuted expvals
// E = (d1d2d3, d0d1, d0d1d2, d0d1d2d3).  exp2-form activations with
// log2e folded into Wout.  Packed-f32 (v_pk_*) math throughout.
// Each lane owns hidden units j = 2*lane, 2*lane+1.
// ============================================================
__global__ __launch_bounds__(64)
void qlstm_rec(const float* __restrict__ Win_w,
               const float* __restrict__ Wout_w,
               const float* __restrict__ Wout_b,
               const float* __restrict__ w_f,
               const float* __restrict__ w_i,
               const float* __restrict__ w_u,
               const float* __restrict__ w_o,
               const float* __restrict__ yx,
               float* __restrict__ out)
{
  const int lane = threadIdx.x;
  const int b    = blockIdx.x;
  const int j0   = 2*lane, j1 = 2*lane + 1;

  constexpr float L2E  = 1.4426950408889634f;   // log2(e)
  constexpr float NL2E = -L2E;                  // sigmoid prescale
  constexpr float T2E  = 2.0f * L2E;            // tanh prescale

  // recurrent weights Wh[q][j]
  float whA[4], whB[4];
  #pragma unroll
  for (int q = 0; q < 4; ++q) {
    whA[q] = Win_w[q*256 + j0];
    whB[q] = Win_w[q*256 + j1];
  }
  // Wout rows for this lane's two units, prescaled for exp2-form activations
  f2 wo_s[4], wo_t[4];
  #pragma unroll
  for (int k = 0; k < 4; ++k) {
    const float a = Wout_w[j0*4 + k], bb = Wout_w[j1*4 + k];
    wo_s[k] = (f2){ a * NL2E, bb * NL2E };
    wo_t[k] = (f2){ a * T2E,  bb * T2E };
  }
  const float wbA = Wout_b[j0], wbB = Wout_b[j1];
  const f2 wb_s = (f2){ wbA * NL2E, wbB * NL2E };
  const f2 wb_t = (f2){ wbA * T2E,  wbB * T2E };

  // ring RY weights: -cos/-sin packed per qubit-pair, per gate (uniform)
  f2 ncw01[4], ncw23[4], nsw01[4], nsw23[4];
  const float* ws[4] = { w_f, w_i, w_u, w_o };
  #pragma unroll
  for (int g = 0; g < 4; ++g) {
    ncw01[g] = (f2){ -cosf(ws[g][0]), -cosf(ws[g][1]) };
    ncw23[g] = (f2){ -cosf(ws[g][2]), -cosf(ws[g][3]) };
    nsw01[g] = (f2){ -sinf(ws[g][0]), -sinf(ws[g][1]) };
    nsw23[g] = (f2){ -sinf(ws[g][2]), -sinf(ws[g][3]) };
  }

  f2 h = (f2){0.f, 0.f};
  f2 c = (f2){0.f, 0.f};

  const float4* yxb = reinterpret_cast<const float4*>(yx) + (size_t)b * TT;
  float4 yn = yxb[0];

  float* outseq = out + (size_t)b * TT * HH;

  for (int t = 0; t < TT; ++t) {
    const float4 yc = yn;
    yn = yxb[(t + 1 < TT) ? t + 1 : t];

    // ---- y = Wh @ h + y_x  (cross-lane reduce; DPP + permlane) ----
    float r0 = fmaf(h.x, whA[0], h.y * whB[0]);
    float r1 = fmaf(h.x, whA[1], h.y * whB[1]);
    float r2 = fmaf(h.x, whA[2], h.y * whB[2]);
    float r3 = fmaf(h.x, whA[3], h.y * whB[3]);
    r0 = red64(r0); r1 = red64(r1); r2 = red64(r2); r3 = red64(r3);
    const f2 y01 = (f2){ r0 + yc.x, r1 + yc.y };
    const f2 y23 = (f2){ r2 + yc.z, r3 + yc.w };

    // ---- per-qubit A = y*r, B = r*rr (packed, 8 scalar rsq) ----
    const f2 y2a = y01 * y01, y2b = y23 * y23;
    const f2 p1a = y2a + 1.f, p1b = y2b + 1.f;
    const f2 p2a = pkfma(y2a, y2a, splat(1.f));
    const f2 p2b = pkfma(y2b, y2b, splat(1.f));
    const f2 rA  = (f2){ rsq_f(p1a.x), rsq_f(p1a.y) };
    const f2 rB  = (f2){ rsq_f(p1b.x), rsq_f(p1b.y) };
    const f2 rrA = (f2){ rsq_f(p2a.x), rsq_f(p2a.y) };
    const f2 rrB = (f2){ rsq_f(p2b.x), rsq_f(p2b.y) };
    const f2 A01 = y01 * rA, A23 = y23 * rB;
    const f2 B01 = rA * rrA, B23 = rB * rrB;

    // ---- per-gate expvals + prescaled z projections (packed over j0,j1) ----
    f2 z[4];
    #pragma unroll
    for (int g = 0; g < 4; ++g) {
      const f2 d01 = pkfma(ncw01[g], A01, nsw01[g] * B01);
      const f2 d23 = pkfma(ncw23[g], A23, nsw23[g] * B23);
      const float e1 = d01.x * d01.y;      // d0*d1
      const float dp = d23.x * d23.y;      // d2*d3
      const float e0 = d01.y * dp;         // d1*d2*d3
      const float e2 = e1 * d23.x;         // d0*d1*d2
      const float e3 = e1 * dp;            // d0*d1*d2*d3
      const f2* wo = (g == 2) ? wo_t : wo_s;
      const f2  wb = (g == 2) ? wb_t : wb_s;
      z[g] = pkfma(splat(e0), wo[0],
             pkfma(splat(e1), wo[1],
             pkfma(splat(e2), wo[2],
             pkfma(splat(e3), wo[3], wb))));
    }

    // ---- activations: sigmoid = rcp(1+exp2(z')), tanh = 1-2*rcp(1+exp2(z')) ----
    const f2 exf = (f2){ ex2_f(z[0].x), ex2_f(z[0].y) };
    const f2 exi = (f2){ ex2_f(z[1].x), ex2_f(z[1].y) };
    const f2 exu = (f2){ ex2_f(z[2].x), ex2_f(z[2].y) };
    const f2 exo = (f2){ ex2_f(z[3].x), ex2_f(z[3].y) };
    const f2 dnf = exf + 1.f, dni = exi + 1.f, dnu = exu + 1.f, dno = exo + 1.f;
    const f2 fg = (f2){ rcp_f(dnf.x), rcp_f(dnf.y) };
    const f2 ig = (f2){ rcp_f(dni.x), rcp_f(dni.y) };
    const f2 ru = (f2){ rcp_f(dnu.x), rcp_f(dnu.y) };
    const f2 og = (f2){ rcp_f(dno.x), rcp_f(dno.y) };
    const f2 gg = pkfma(splat(-2.f), ru, splat(1.f));

    // ---- LSTM state update ----
    c = pkfma(fg, c, ig * gg);
    const f2 ce = c * T2E;
    const f2 exc = (f2){ ex2_f(ce.x), ex2_f(ce.y) };
    const f2 dnc = exc + 1.f;
    const f2 rc  = (f2){ rcp_f(dnc.x), rcp_f(dnc.y) };
    const f2 th  = pkfma(splat(-2.f), rc, splat(1.f));
    h = og * th;

    *reinterpret_cast<f2*>(outseq + (size_t)t * HH + j0) = h;
  }

  const size_t hoff = (size_t)BB * TT * HH;
  *reinterpret_cast<f2*>(out + hoff + (size_t)b * HH + j0) = h;
  const size_t coff = hoff + (size_t)BB * HH;
  *reinterpret_cast<f2*>(out + coff + (size_t)b * HH + j0) = c;
}

extern "C" void kernel_launch(void* const* d_in, const int* in_sizes, int n_in,
                              void* d_out, int out_size, void* d_ws, size_t ws_size,
                              hipStream_t stream) {
  const float* x      = (const float*)d_in[0];
  const float* Win_w  = (const float*)d_in[1];
  const float* Win_b  = (const float*)d_in[2];
  const float* Wout_w = (const float*)d_in[3];
  const float* Wout_b = (const float*)d_in[4];
  const float* w_f    = (const float*)d_in[5];
  const float* w_i    = (const float*)d_in[6];
  const float* w_u    = (const float*)d_in[7];
  const float* w_o    = (const float*)d_in[8];
  float* out = (float*)d_out;
  float* yx  = (float*)d_ws;   // B*T*4 floats = 2 MB scratch

  const int rows = BB * TT;          // 131072
  const int rowsPerBlk = 64;
  yx_pre<<<rows / rowsPerBlk, 64, 0, stream>>>(x, Win_w, Win_b, yx, rowsPerBlk);
  qlstm_rec<<<BB, 64, 0, stream>>>(Win_w, Wout_w, Wout_b, w_f, w_i, w_u, w_o, yx, out);
}

// Round 4
// 257.622 us; speedup vs baseline: 1.8481x; 1.0701x over previous
//
#include <hip/hip_runtime.h>

#define DEVINL __device__ __forceinline__

constexpr int BB = 256;   // batch
constexpr int TT = 512;   // time steps
constexpr int FF = 128;   // features
constexpr int HH = 128;   // hidden size

typedef float f2 __attribute__((ext_vector_type(2)));

DEVINL f2 pkfma(f2 a, f2 b, f2 c) { return __builtin_elementwise_fma(a, b, c); }
DEVINL f2 splat(float s) { return (f2){s, s}; }
DEVINL f2 bx(f2 v) { return (f2){v.x, v.x}; }   // broadcast lo (op_sel)
DEVINL f2 by(f2 v) { return (f2){v.y, v.y}; }   // broadcast hi (op_sel)

// ---- DPP cross-lane helpers (all-lanes-active call sites only) ----
template<int CTRL>
DEVINL float dppf(float x) {
  return __builtin_bit_cast(float,
    __builtin_amdgcn_update_dpp(0, __builtin_bit_cast(int, x), CTRL, 0xF, 0xF, true));
}

// allreduce within each 16-lane row (values end uniform per row)
DEVINL float red16(float v) {
  v += dppf<0xB1>(v);    // quad_perm [1,0,3,2]  == xor 1
  v += dppf<0x4E>(v);    // quad_perm [2,3,0,1]  == xor 2
  v += dppf<0x141>(v);   // row_half_mirror      (== xor 4 here)
  v += dppf<0x140>(v);   // row_mirror           (== xor 8 here)
  return v;
}

// v_permlane16_swap: odd 16-rows of a <-> even 16-rows of b.  With a=b=v and
// a following add this sums row pairs (0,1) and (2,3) -> uniform per 32-half.
DEVINL float swap16add(float v) {
  float a = v, b = v;
  asm("s_nop 0\n\tv_permlane16_swap_b32 %0, %1" : "+v"(a), "+v"(b));
  return a + b;
}
DEVINL float swap32add(float v) {
  float a = v, b = v;
  asm("s_nop 0\n\tv_permlane32_swap_b32 %0, %1" : "+v"(a), "+v"(b));
  return a + b;
}
DEVINL float red32h(float v) { return swap16add(red16(v)); } // per-half allreduce
DEVINL float red64(float v)  { return swap32add(swap16add(red16(v))); }

DEVINL float rcp_f(float x){ return __builtin_amdgcn_rcpf(x); }
DEVINL float rsq_f(float x){ return __builtin_amdgcn_rsqf(x); }
DEVINL float ex2_f(float x){ return __builtin_amdgcn_exp2f(x); }
DEVINL f2 ex2_2(f2 v){ return (f2){ ex2_f(v.x), ex2_f(v.y) }; }
DEVINL f2 rcp_2(f2 v){ return (f2){ rcp_f(v.x), rcp_f(v.y) }; }

// ============================================================
// Kernel 1: y_x[r][q] = sum_f x[r][f] * Win_w[q][128+f] + Win_b[q]
// ============================================================
__global__ __launch_bounds__(64)
void yx_pre(const float* __restrict__ x,
            const float* __restrict__ Win_w,
            const float* __restrict__ Win_b,
            float* __restrict__ yx, int rowsPerBlk)
{
  const int lane = threadIdx.x;
  const float wx0a = Win_w[0*256 + 128 + 2*lane], wx0b = Win_w[0*256 + 129 + 2*lane];
  const float wx1a = Win_w[1*256 + 128 + 2*lane], wx1b = Win_w[1*256 + 129 + 2*lane];
  const float wx2a = Win_w[2*256 + 128 + 2*lane], wx2b = Win_w[2*256 + 129 + 2*lane];
  const float wx3a = Win_w[3*256 + 128 + 2*lane], wx3b = Win_w[3*256 + 129 + 2*lane];
  const float bb0 = Win_b[0], bb1 = Win_b[1], bb2 = Win_b[2], bb3 = Win_b[3];

  const int r0 = blockIdx.x * rowsPerBlk;
  float2 xv = *reinterpret_cast<const float2*>(x + (size_t)r0 * FF + 2*lane);
  for (int k = 0; k < rowsPerBlk; ++k) {
    const int r = r0 + k;
    float2 cur = xv;
    if (k + 1 < rowsPerBlk)
      xv = *reinterpret_cast<const float2*>(x + (size_t)(r + 1) * FF + 2*lane);
    float p0 = fmaf(cur.x, wx0a, cur.y * wx0b);
    float p1 = fmaf(cur.x, wx1a, cur.y * wx1b);
    float p2 = fmaf(cur.x, wx2a, cur.y * wx2b);
    float p3 = fmaf(cur.x, wx3a, cur.y * wx3b);
    p0 = red64(p0); p1 = red64(p1); p2 = red64(p2); p3 = red64(p3);
    if (lane == 0)
      reinterpret_cast<float4*>(yx)[r] = make_float4(p0 + bb0, p1 + bb1, p2 + bb2, p3 + bb3);
  }
}

// ============================================================
// Kernel 2: recurrent scan — TWO chains per wave (lanes 0-31 / 32-63),
// 4 hidden units per lane.  Analytic VQC (d_q = -r(y cos w + rr sin w),
// ring-permuted E = (d1d2d3, d0d1, d0d1d2, d0d1d2d3)), d/E packed across
// gate pairs (f,i)|(u,o), exp2-form activations with one-rcp fused
// c-update:  c' = (c(1+b)(u+1) + (1+a)(u-1)) / ((1+a)(1+b)(u+1)),
//            h  = (v-1) / ((1+d)(v+1)),  v = e^{2c'}.
// ============================================================
__global__ __launch_bounds__(64)
void qlstm_rec(const float* __restrict__ Win_w,
               const float* __restrict__ Wout_w,
               const float* __restrict__ Wout_b,
               const float* __restrict__ w_f,
               const float* __restrict__ w_i,
               const float* __restrict__ w_u,
               const float* __restrict__ w_o,
               const float* __restrict__ yx,
               float* __restrict__ out)
{
  const int lane  = threadIdx.x;
  const int half  = lane >> 5;
  const int hq    = lane & 31;
  const int chain = 2 * blockIdx.x + half;
  const int j0    = 4 * hq;

  constexpr float L2E  = 1.4426950408889634f;
  constexpr float NL2E = -L2E;          // sigmoid prescale
  constexpr float T2E  = 2.0f * L2E;    // tanh prescale

  // Wh[k][j0..j0+3]
  f2 wh01[4], wh23[4];
  #pragma unroll
  for (int k = 0; k < 4; ++k) {
    const float4 w = *reinterpret_cast<const float4*>(Win_w + k*256 + j0);
    wh01[k] = (f2){w.x, w.y};
    wh23[k] = (f2){w.z, w.w};
  }

  // Wout rows for the 4 units, transposed and prescaled
  const float4 q0 = reinterpret_cast<const float4*>(Wout_w)[j0+0];
  const float4 q1 = reinterpret_cast<const float4*>(Wout_w)[j0+1];
  const float4 q2 = reinterpret_cast<const float4*>(Wout_w)[j0+2];
  const float4 q3 = reinterpret_cast<const float4*>(Wout_w)[j0+3];
  const float a0[4] = {q0.x, q0.y, q0.z, q0.w};
  const float a1[4] = {q1.x, q1.y, q1.z, q1.w};
  const float a2[4] = {q2.x, q2.y, q2.z, q2.w};
  const float a3[4] = {q3.x, q3.y, q3.z, q3.w};
  f2 wos01[4], wos23[4], wot01[4], wot23[4];
  #pragma unroll
  for (int k = 0; k < 4; ++k) {
    wos01[k] = (f2){ a0[k]*NL2E, a1[k]*NL2E };
    wos23[k] = (f2){ a2[k]*NL2E, a3[k]*NL2E };
    wot01[k] = (f2){ a0[k]*T2E,  a1[k]*T2E  };
    wot23[k] = (f2){ a2[k]*T2E,  a3[k]*T2E  };
  }
  const f2 wbs01 = (f2){ Wout_b[j0+0]*NL2E, Wout_b[j0+1]*NL2E };
  const f2 wbs23 = (f2){ Wout_b[j0+2]*NL2E, Wout_b[j0+3]*NL2E };
  const f2 wbt01 = (f2){ Wout_b[j0+0]*T2E,  Wout_b[j0+1]*T2E  };
  const f2 wbt23 = (f2){ Wout_b[j0+2]*T2E,  Wout_b[j0+3]*T2E  };

  // ring RY coefficients packed across gate pairs (f,i) and (u,o)
  f2 cwfi[4], swfi[4], cwuo[4], swuo[4];
  #pragma unroll
  for (int q = 0; q < 4; ++q) {
    cwfi[q] = (f2){ -cosf(w_f[q]), -cosf(w_i[q]) };
    swfi[q] = (f2){ -sinf(w_f[q]), -sinf(w_i[q]) };
    cwuo[q] = (f2){ -cosf(w_u[q]), -cosf(w_o[q]) };
    swuo[q] = (f2){ -sinf(w_u[q]), -sinf(w_o[q]) };
  }

  f2 h01 = splat(0.f), h23 = splat(0.f);
  f2 c01 = splat(0.f), c23 = splat(0.f);

  const float4* yxb = reinterpret_cast<const float4*>(yx) + (size_t)chain * TT;
  float4 yn = yxb[0];

  float* outseq = out + (size_t)chain * TT * HH;

  for (int t = 0; t < TT; ++t) {
    const float4 yc = yn;
    yn = yxb[(t + 1 < TT) ? t + 1 : t];

    // ---- y = Wh @ h + y_x  (per-half reduce: DPP + permlane16_swap) ----
    const f2 pp0 = pkfma(h01, wh01[0], h23 * wh23[0]);
    const f2 pp1 = pkfma(h01, wh01[1], h23 * wh23[1]);
    const f2 pp2 = pkfma(h01, wh01[2], h23 * wh23[2]);
    const f2 pp3 = pkfma(h01, wh01[3], h23 * wh23[3]);
    const float s0 = red32h(pp0.x + pp0.y);
    const float s1 = red32h(pp1.x + pp1.y);
    const float s2 = red32h(pp2.x + pp2.y);
    const float s3 = red32h(pp3.x + pp3.y);
    const f2 y01 = (f2){ s0 + yc.x, s1 + yc.y };
    const f2 y23 = (f2){ s2 + yc.z, s3 + yc.w };

    // ---- per-qubit A = y*r, B = r*rr ----
    const f2 y2a = y01 * y01, y2b = y23 * y23;
    const f2 p1a = y2a + 1.f, p1b = y2b + 1.f;
    const f2 p2a = pkfma(y2a, y2a, splat(1.f));
    const f2 p2b = pkfma(y2b, y2b, splat(1.f));
    const f2 rA  = (f2){ rsq_f(p1a.x), rsq_f(p1a.y) };
    const f2 rB  = (f2){ rsq_f(p1b.x), rsq_f(p1b.y) };
    const f2 rrA = (f2){ rsq_f(p2a.x), rsq_f(p2a.y) };
    const f2 rrB = (f2){ rsq_f(p2b.x), rsq_f(p2b.y) };
    const f2 A01 = y01 * rA, A23 = y23 * rB;
    const f2 B01 = rA * rrA, B23 = rB * rrB;

    // ---- d packs per gate pair, E products (elementwise over the pair) ----
    const f2 d0fi = pkfma(cwfi[0], bx(A01), swfi[0] * bx(B01));
    const f2 d1fi = pkfma(cwfi[1], by(A01), swfi[1] * by(B01));
    const f2 d2fi = pkfma(cwfi[2], bx(A23), swfi[2] * bx(B23));
    const f2 d3fi = pkfma(cwfi[3], by(A23), swfi[3] * by(B23));
    const f2 d0uo = pkfma(cwuo[0], bx(A01), swuo[0] * bx(B01));
    const f2 d1uo = pkfma(cwuo[1], by(A01), swuo[1] * by(B01));
    const f2 d2uo = pkfma(cwuo[2], bx(A23), swuo[2] * bx(B23));
    const f2 d3uo = pkfma(cwuo[3], by(A23), swuo[3] * by(B23));

    const f2 e1fi = d0fi * d1fi, dpfi = d2fi * d3fi;
    const f2 e0fi = d1fi * dpfi, e2fi = e1fi * d2fi, e3fi = e1fi * dpfi;
    const f2 e1uo = d0uo * d1uo, dpuo = d2uo * d3uo;
    const f2 e0uo = d1uo * dpuo, e2uo = e1uo * d2uo, e3uo = e1uo * dpuo;

    // ---- z projections (prescaled), f uses .x of fi-packs, i uses .y, etc. ----
    const f2 zf01 = pkfma(bx(e0fi), wos01[0], pkfma(bx(e1fi), wos01[1],
                    pkfma(bx(e2fi), wos01[2], pkfma(bx(e3fi), wos01[3], wbs01))));
    const f2 zf23 = pkfma(bx(e0fi), wos23[0], pkfma(bx(e1fi), wos23[1],
                    pkfma(bx(e2fi), wos23[2], pkfma(bx(e3fi), wos23[3], wbs23))));
    const f2 zi01 = pkfma(by(e0fi), wos01[0], pkfma(by(e1fi), wos01[1],
                    pkfma(by(e2fi), wos01[2], pkfma(by(e3fi), wos01[3], wbs01))));
    const f2 zi23 = pkfma(by(e0fi), wos23[0], pkfma(by(e1fi), wos23[1],
                    pkfma(by(e2fi), wos23[2], pkfma(by(e3fi), wos23[3], wbs23))));
    const f2 zu01 = pkfma(bx(e0uo), wot01[0], pkfma(bx(e1uo), wot01[1],
                    pkfma(bx(e2uo), wot01[2], pkfma(bx(e3uo), wot01[3], wbt01))));
    const f2 zu23 = pkfma(bx(e0uo), wot23[0], pkfma(bx(e1uo), wot23[1],
                    pkfma(bx(e2uo), wot23[2], pkfma(bx(e3uo), wot23[3], wbt23))));
    const f2 zo01 = pkfma(by(e0uo), wos01[0], pkfma(by(e1uo), wos01[1],
                    pkfma(by(e2uo), wos01[2], pkfma(by(e3uo), wos01[3], wbs01))));
    const f2 zo23 = pkfma(by(e0uo), wos23[0], pkfma(by(e1uo), wos23[1],
                    pkfma(by(e2uo), wos23[2], pkfma(by(e3uo), wos23[3], wbs23))));

    // ---- exp2: a=e^{-zf}, b=e^{-zi}, u=e^{2zu}, d=e^{-zo} ----
    const f2 ea01 = ex2_2(zf01), ea23 = ex2_2(zf23);
    const f2 eb01 = ex2_2(zi01), eb23 = ex2_2(zi23);
    const f2 eu01 = ex2_2(zu01), eu23 = ex2_2(zu23);
    const f2 ed01 = ex2_2(zo01), ed23 = ex2_2(zo23);

    // ---- fused c update (one rcp per f2) ----
    {
      const f2 u1 = eu01 + 1.f, b1 = eb01 + 1.f, aa = ea01 + 1.f, um = eu01 - 1.f;
      const f2 t1 = b1 * u1;
      const f2 num = pkfma(c01, t1, aa * um);
      const f2 den = aa * t1;
      c01 = num * rcp_2(den);
    }
    {
      const f2 u1 = eu23 + 1.f, b1 = eb23 + 1.f, aa = ea23 + 1.f, um = eu23 - 1.f;
      const f2 t1 = b1 * u1;
      const f2 num = pkfma(c23, t1, aa * um);
      const f2 den = aa * t1;
      c23 = num * rcp_2(den);
    }

    // ---- h = o * tanh(c') = (v-1)/((1+d)(v+1)), one rcp per f2 ----
    {
      const f2 v  = ex2_2(c01 * T2E);
      const f2 vm = v - 1.f, vp = v + 1.f, dd = ed01 + 1.f;
      h01 = vm * rcp_2(dd * vp);
    }
    {
      const f2 v  = ex2_2(c23 * T2E);
      const f2 vm = v - 1.f, vp = v + 1.f, dd = ed23 + 1.f;
      h23 = vm * rcp_2(dd * vp);
    }

    *reinterpret_cast<float4*>(outseq + (size_t)t * HH + j0) =
        make_float4(h01.x, h01.y, h23.x, h23.y);
  }

  const size_t hoff = (size_t)BB * TT * HH;
  *reinterpret_cast<float4*>(out + hoff + (size_t)chain * HH + j0) =
      make_float4(h01.x, h01.y, h23.x, h23.y);
  const size_t coff = hoff + (size_t)BB * HH;
  *reinterpret_cast<float4*>(out + coff + (size_t)chain * HH + j0) =
      make_float4(c01.x, c01.y, c23.x, c23.y);
}

extern "C" void kernel_launch(void* const* d_in, const int* in_sizes, int n_in,
                              void* d_out, int out_size, void* d_ws, size_t ws_size,
                              hipStream_t stream) {
  const float* x      = (const float*)d_in[0];
  const float* Win_w  = (const float*)d_in[1];
  const float* Win_b  = (const float*)d_in[2];
  const float* Wout_w = (const float*)d_in[3];
  const float* Wout_b = (const float*)d_in[4];
  const float* w_f    = (const float*)d_in[5];
  const float* w_i    = (const float*)d_in[6];
  const float* w_u    = (const float*)d_in[7];
  const float* w_o    = (const float*)d_in[8];
  float* out = (float*)d_out;
  float* yx  = (float*)d_ws;   // B*T*4 floats = 2 MB scratch

  const int rows = BB * TT;          // 131072
  const int rowsPerBlk = 64;
  yx_pre<<<rows / rowsPerBlk, 64, 0, stream>>>(x, Win_w, Win_b, yx, rowsPerBlk);
  qlstm_rec<<<BB/2, 64, 0, stream>>>(Win_w, Wout_w, Wout_b, w_f, w_i, w_u, w_o, yx, out);
}

// Round 5
// 242.991 us; speedup vs baseline: 1.9593x; 1.0602x over previous
//
#include <hip/hip_runtime.h>

#define DEVINL __device__ __forceinline__

constexpr int BB = 256;   // batch
constexpr int TT = 512;   // time steps
constexpr int FF = 128;   // features
constexpr int HH = 128;   // hidden size

typedef float f2 __attribute__((ext_vector_type(2)));

DEVINL f2 pkfma(f2 a, f2 b, f2 c) { return __builtin_elementwise_fma(a, b, c); }
DEVINL f2 splat(float s) { return (f2){s, s}; }

// ---- DPP cross-lane helpers (all-lanes-active call sites only) ----
template<int CTRL>
DEVINL float dppf(float x) {
  return __builtin_bit_cast(float,
    __builtin_amdgcn_update_dpp(0, __builtin_bit_cast(int, x), CTRL, 0xF, 0xF, true));
}

// allreduce within each 16-lane row (values end uniform per row)
DEVINL float red16(float v) {
  v += dppf<0xB1>(v);    // quad_perm [1,0,3,2]  == xor 1
  v += dppf<0x4E>(v);    // quad_perm [2,3,0,1]  == xor 2
  v += dppf<0x141>(v);   // row_half_mirror      (== xor 4 here)
  v += dppf<0x140>(v);   // row_mirror           (== xor 8 here)
  return v;
}

DEVINL float swap16add(float v) {
  float a = v, b = v;
  asm("s_nop 0\n\tv_permlane16_swap_b32 %0, %1" : "+v"(a), "+v"(b));
  return a + b;
}
DEVINL float swap32add(float v) {
  float a = v, b = v;
  asm("s_nop 0\n\tv_permlane32_swap_b32 %0, %1" : "+v"(a), "+v"(b));
  return a + b;
}
DEVINL float red64(float v)  { return swap32add(swap16add(red16(v))); }

DEVINL float rcp_f(float x){ return __builtin_amdgcn_rcpf(x); }
DEVINL float rsq_f(float x){ return __builtin_amdgcn_rsqf(x); }
DEVINL float ex2_f(float x){ return __builtin_amdgcn_exp2f(x); }
DEVINL f2 ex2_2(f2 v){ return (f2){ ex2_f(v.x), ex2_f(v.y) }; }

// ============================================================
// Kernel 1: y_x[r][q] = sum_f x[r][f] * Win_w[q][128+f] + Win_b[q]
// ============================================================
__global__ __launch_bounds__(64)
void yx_pre(const float* __restrict__ x,
            const float* __restrict__ Win_w,
            const float* __restrict__ Win_b,
            float* __restrict__ yx, int rowsPerBlk)
{
  const int lane = threadIdx.x;
  const float wx0a = Win_w[0*256 + 128 + 2*lane], wx0b = Win_w[0*256 + 129 + 2*lane];
  const float wx1a = Win_w[1*256 + 128 + 2*lane], wx1b = Win_w[1*256 + 129 + 2*lane];
  const float wx2a = Win_w[2*256 + 128 + 2*lane], wx2b = Win_w[2*256 + 129 + 2*lane];
  const float wx3a = Win_w[3*256 + 128 + 2*lane], wx3b = Win_w[3*256 + 129 + 2*lane];
  const float bb0 = Win_b[0], bb1 = Win_b[1], bb2 = Win_b[2], bb3 = Win_b[3];

  const int r0 = blockIdx.x * rowsPerBlk;
  float2 xv = *reinterpret_cast<const float2*>(x + (size_t)r0 * FF + 2*lane);
  for (int k = 0; k < rowsPerBlk; ++k) {
    const int r = r0 + k;
    float2 cur = xv;
    if (k + 1 < rowsPerBlk)
      xv = *reinterpret_cast<const float2*>(x + (size_t)(r + 1) * FF + 2*lane);
    float p0 = fmaf(cur.x, wx0a, cur.y * wx0b);
    float p1 = fmaf(cur.x, wx1a, cur.y * wx1b);
    float p2 = fmaf(cur.x, wx2a, cur.y * wx2b);
    float p3 = fmaf(cur.x, wx3a, cur.y * wx3b);
    p0 = red64(p0); p1 = red64(p1); p2 = red64(p2); p3 = red64(p3);
    if (lane == 0)
      reinterpret_cast<float4*>(yx)[r] = make_float4(p0 + bb0, p1 + bb1, p2 + bb2, p3 + bb3);
  }
}

// ============================================================
// Kernel 2: recurrent scan — ONE chain per wave, 2 units/lane.
// Analytic VQC; d/E packed across gate pairs (f,i)|(u,o); z packed
// across gate pairs per unit with PRE-HOISTED weight packs (no in-loop
// broadcasts); exp2-form activations; one-rcp fused c and h updates.
// ============================================================
__global__ __launch_bounds__(64)
void qlstm_rec(const float* __restrict__ Win_w,
               const float* __restrict__ Wout_w,
               const float* __restrict__ Wout_b,
               const float* __restrict__ w_f,
               const float* __restrict__ w_i,
               const float* __restrict__ w_u,
               const float* __restrict__ w_o,
               const float* __restrict__ yx,
               float* __restrict__ out)
{
  const int lane = threadIdx.x;
  const int b    = blockIdx.x;
  const int j0   = 2*lane, j1 = 2*lane + 1;

  constexpr float L2E  = 1.4426950408889634f;
  constexpr float NL2E = -L2E;          // sigmoid prescale (f,i,o)
  constexpr float T2E  = 2.0f * L2E;    // tanh prescale (u, and tanh(c))

  // recurrent weights Wh[q][j0], Wh[q][j1]
  float whA[4], whB[4];
  #pragma unroll
  for (int q = 0; q < 4; ++q) {
    whA[q] = Win_w[q*256 + j0];
    whB[q] = Win_w[q*256 + j1];
  }

  // z weight packs per unit: fi-pair shares NL2E on both halves;
  // uo-pair = {T2E (u), NL2E (o)}.  Hoisted: no in-loop broadcasts.
  const float4 r0v = reinterpret_cast<const float4*>(Wout_w)[j0];
  const float4 r1v = reinterpret_cast<const float4*>(Wout_w)[j1];
  const float w0[4] = {r0v.x, r0v.y, r0v.z, r0v.w};
  const float w1[4] = {r1v.x, r1v.y, r1v.z, r1v.w};
  f2 wfi0[4], wfi1[4], wuo0[4], wuo1[4];
  #pragma unroll
  for (int k = 0; k < 4; ++k) {
    wfi0[k] = (f2){ w0[k]*NL2E, w0[k]*NL2E };
    wfi1[k] = (f2){ w1[k]*NL2E, w1[k]*NL2E };
    wuo0[k] = (f2){ w0[k]*T2E,  w0[k]*NL2E };
    wuo1[k] = (f2){ w1[k]*T2E,  w1[k]*NL2E };
  }
  const float b0s = Wout_b[j0], b1s = Wout_b[j1];
  const f2 bfi0 = (f2){ b0s*NL2E, b0s*NL2E };
  const f2 bfi1 = (f2){ b1s*NL2E, b1s*NL2E };
  const f2 buo0 = (f2){ b0s*T2E,  b0s*NL2E };
  const f2 buo1 = (f2){ b1s*T2E,  b1s*NL2E };

  // ring RY coefficients packed across gate pairs (f,i) and (u,o)
  f2 cwfi[4], swfi[4], cwuo[4], swuo[4];
  #pragma unroll
  for (int q = 0; q < 4; ++q) {
    cwfi[q] = (f2){ -cosf(w_f[q]), -cosf(w_i[q]) };
    swfi[q] = (f2){ -sinf(w_f[q]), -sinf(w_i[q]) };
    cwuo[q] = (f2){ -cosf(w_u[q]), -cosf(w_o[q]) };
    swuo[q] = (f2){ -sinf(w_u[q]), -sinf(w_o[q]) };
  }

  float h0 = 0.f, h1 = 0.f, c0 = 0.f, c1 = 0.f;

  const float4* yxb = reinterpret_cast<const float4*>(yx) + (size_t)b * TT;
  float4 yn = yxb[0];

  float* outseq = out + (size_t)b * TT * HH;

  for (int t = 0; t < TT; ++t) {
    const float4 yc = yn;
    yn = yxb[(t + 1 < TT) ? t + 1 : t];

    // ---- y = Wh @ h + y_x  (DPP + permlane allreduce over 64 lanes) ----
    float s0 = fmaf(h0, whA[0], h1 * whB[0]);
    float s1 = fmaf(h0, whA[1], h1 * whB[1]);
    float s2 = fmaf(h0, whA[2], h1 * whB[2]);
    float s3 = fmaf(h0, whA[3], h1 * whB[3]);
    s0 = red64(s0); s1 = red64(s1); s2 = red64(s2); s3 = red64(s3);
    const float y0 = s0 + yc.x, y1 = s1 + yc.y;
    const float y2 = s2 + yc.z, y3 = s3 + yc.w;

    // ---- per-qubit A = y*r, B = r*rr (packed over qubit pairs) ----
    const f2 y01 = (f2){y0, y1}, y23 = (f2){y2, y3};
    const f2 y2a = y01 * y01, y2b = y23 * y23;
    const f2 p1a = y2a + 1.f, p1b = y2b + 1.f;
    const f2 p2a = pkfma(y2a, y2a, splat(1.f));
    const f2 p2b = pkfma(y2b, y2b, splat(1.f));
    const f2 rA  = (f2){ rsq_f(p1a.x), rsq_f(p1a.y) };
    const f2 rB  = (f2){ rsq_f(p1b.x), rsq_f(p1b.y) };
    const f2 rrA = (f2){ rsq_f(p2a.x), rsq_f(p2a.y) };
    const f2 rrB = (f2){ rsq_f(p2b.x), rsq_f(p2b.y) };
    const f2 A01 = y01 * rA, A23 = y23 * rB;
    const f2 B01 = rA * rrA, B23 = rB * rrB;

    // broadcasts of A_q, B_q for the gate-pair packed d's
    const f2 bA0 = splat(A01.x), bA1 = splat(A01.y);
    const f2 bA2 = splat(A23.x), bA3 = splat(A23.y);
    const f2 bB0 = splat(B01.x), bB1 = splat(B01.y);
    const f2 bB2 = splat(B23.x), bB3 = splat(B23.y);

    // ---- d packs per gate pair, E products ----
    const f2 d0fi = pkfma(cwfi[0], bA0, swfi[0] * bB0);
    const f2 d1fi = pkfma(cwfi[1], bA1, swfi[1] * bB1);
    const f2 d2fi = pkfma(cwfi[2], bA2, swfi[2] * bB2);
    const f2 d3fi = pkfma(cwfi[3], bA3, swfi[3] * bB3);
    const f2 d0uo = pkfma(cwuo[0], bA0, swuo[0] * bB0);
    const f2 d1uo = pkfma(cwuo[1], bA1, swuo[1] * bB1);
    const f2 d2uo = pkfma(cwuo[2], bA2, swuo[2] * bB2);
    const f2 d3uo = pkfma(cwuo[3], bA3, swuo[3] * bB3);

    const f2 e1fi = d0fi * d1fi, dpfi = d2fi * d3fi;
    const f2 e0fi = d1fi * dpfi, e2fi = e1fi * d2fi, e3fi = e1fi * dpfi;
    const f2 e1uo = d0uo * d1uo, dpuo = d2uo * d3uo;
    const f2 e0uo = d1uo * dpuo, e2uo = e1uo * d2uo, e3uo = e1uo * dpuo;

    // ---- z packs {zf,zi} and {zu,zo} per unit (weights pre-hoisted) ----
    const f2 zfi0 = pkfma(e0fi, wfi0[0], pkfma(e1fi, wfi0[1],
                    pkfma(e2fi, wfi0[2], pkfma(e3fi, wfi0[3], bfi0))));
    const f2 zfi1 = pkfma(e0fi, wfi1[0], pkfma(e1fi, wfi1[1],
                    pkfma(e2fi, wfi1[2], pkfma(e3fi, wfi1[3], bfi1))));
    const f2 zuo0 = pkfma(e0uo, wuo0[0], pkfma(e1uo, wuo0[1],
                    pkfma(e2uo, wuo0[2], pkfma(e3uo, wuo0[3], buo0))));
    const f2 zuo1 = pkfma(e0uo, wuo1[0], pkfma(e1uo, wuo1[1],
                    pkfma(e2uo, wuo1[2], pkfma(e3uo, wuo1[3], buo1))));

    // ---- activations: exfi = {a, b}, exuo = {u, d} ----
    const f2 exfi0 = ex2_2(zfi0), exfi1 = ex2_2(zfi1);
    const f2 exuo0 = ex2_2(zuo0), exuo1 = ex2_2(zuo1);
    const f2 pfi0 = exfi0 + 1.f, pfi1 = exfi1 + 1.f;   // {1+a, 1+b}
    const f2 puo0 = exuo0 + 1.f, puo1 = exuo1 + 1.f;   // {1+u, 1+d}
    const float um0 = exuo0.x - 1.f, um1 = exuo1.x - 1.f;

    // ---- fused c update: c' = (c(1+b)(u+1) + (1+a)(u-1)) / ((1+a)(1+b)(u+1)) ----
    {
      const float t1 = pfi0.y * puo0.x;
      const float num = fmaf(c0, t1, pfi0.x * um0);
      c0 = num * rcp_f(pfi0.x * t1);
    }
    {
      const float t1 = pfi1.y * puo1.x;
      const float num = fmaf(c1, t1, pfi1.x * um1);
      c1 = num * rcp_f(pfi1.x * t1);
    }

    // ---- h = (v-1)/((1+d)(v+1)), v = exp2(T2E*c') ----
    {
      const float v = ex2_f(c0 * T2E);
      h0 = (v - 1.f) * rcp_f(puo0.y * (v + 1.f));
    }
    {
      const float v = ex2_f(c1 * T2E);
      h1 = (v - 1.f) * rcp_f(puo1.y * (v + 1.f));
    }

    *reinterpret_cast<float2*>(outseq + (size_t)t * HH + j0) = make_float2(h0, h1);
  }

  const size_t hoff = (size_t)BB * TT * HH;
  *reinterpret_cast<float2*>(out + hoff + (size_t)b * HH + j0) = make_float2(h0, h1);
  const size_t coff = hoff + (size_t)BB * HH;
  *reinterpret_cast<float2*>(out + coff + (size_t)b * HH + j0) = make_float2(c0, c1);
}

extern "C" void kernel_launch(void* const* d_in, const int* in_sizes, int n_in,
                              void* d_out, int out_size, void* d_ws, size_t ws_size,
                              hipStream_t stream) {
  const float* x      = (const float*)d_in[0];
  const float* Win_w  = (const float*)d_in[1];
  const float* Win_b  = (const float*)d_in[2];
  const float* Wout_w = (const float*)d_in[3];
  const float* Wout_b = (const float*)d_in[4];
  const float* w_f    = (const float*)d_in[5];
  const float* w_i    = (const float*)d_in[6];
  const float* w_u    = (const float*)d_in[7];
  const float* w_o    = (const float*)d_in[8];
  float* out = (float*)d_out;
  float* yx  = (float*)d_ws;   // B*T*4 floats = 2 MB scratch

  const int rows = BB * TT;          // 131072
  const int rowsPerBlk = 16;
  yx_pre<<<rows / rowsPerBlk, 64, 0, stream>>>(x, Win_w, Win_b, yx, rowsPerBlk);
  qlstm_rec<<<BB, 64, 0, stream>>>(Win_w, Wout_w, Wout_b, w_f, w_i, w_u, w_o, yx, out);
}

// Round 6
// 231.489 us; speedup vs baseline: 2.0567x; 1.0497x over previous
//
#include <hip/hip_runtime.h>

#define DEVINL __device__ __forceinline__

constexpr int BB = 256;   // batch
constexpr int TT = 512;   // time steps
constexpr int FF = 128;   // features
constexpr int HH = 128;   // hidden size

typedef float f2 __attribute__((ext_vector_type(2)));

DEVINL f2 pkfma(f2 a, f2 b, f2 c) { return __builtin_elementwise_fma(a, b, c); }
DEVINL f2 splat(float s) { return (f2){s, s}; }

// ---- DPP cross-lane helpers (all-lanes-active call sites only) ----
template<int CTRL>
DEVINL float dppf(float x) {
  return __builtin_bit_cast(float,
    __builtin_amdgcn_update_dpp(0, __builtin_bit_cast(int, x), CTRL, 0xF, 0xF, true));
}

// allreduce within each 16-lane row (values end uniform per row)
DEVINL float red16(float v) {
  v += dppf<0xB1>(v);    // quad_perm [1,0,3,2]  == xor 1
  v += dppf<0x4E>(v);    // quad_perm [2,3,0,1]  == xor 2
  v += dppf<0x141>(v);   // row_half_mirror      (== xor 4 here)
  v += dppf<0x140>(v);   // row_mirror           (== xor 8 here)
  return v;
}

DEVINL float swap16add(float v) {
  float a = v, b = v;
  asm("s_nop 0\n\tv_permlane16_swap_b32 %0, %1" : "+v"(a), "+v"(b));
  return a + b;
}
DEVINL float swap32add(float v) {
  float a = v, b = v;
  asm("s_nop 0\n\tv_permlane32_swap_b32 %0, %1" : "+v"(a), "+v"(b));
  return a + b;
}
DEVINL float red64(float v)  { return swap32add(swap16add(red16(v))); }

DEVINL float rcp_f(float x){ return __builtin_amdgcn_rcpf(x); }
DEVINL float rsq_f(float x){ return __builtin_amdgcn_rsqf(x); }
DEVINL float ex2_f(float x){ return __builtin_amdgcn_exp2f(x); }
DEVINL f2 ex2_2(f2 v){ return (f2){ ex2_f(v.x), ex2_f(v.y) }; }

// ============================================================
// Kernel 1: y_x[r][q] = sum_f x[r][f] * Win_w[q][128+f] + Win_b[q]
// ============================================================
__global__ __launch_bounds__(64)
void yx_pre(const float* __restrict__ x,
            const float* __restrict__ Win_w,
            const float* __restrict__ Win_b,
            float* __restrict__ yx, int rowsPerBlk)
{
  const int lane = threadIdx.x;
  const float wx0a = Win_w[0*256 + 128 + 2*lane], wx0b = Win_w[0*256 + 129 + 2*lane];
  const float wx1a = Win_w[1*256 + 128 + 2*lane], wx1b = Win_w[1*256 + 129 + 2*lane];
  const float wx2a = Win_w[2*256 + 128 + 2*lane], wx2b = Win_w[2*256 + 129 + 2*lane];
  const float wx3a = Win_w[3*256 + 128 + 2*lane], wx3b = Win_w[3*256 + 129 + 2*lane];
  const float bb0 = Win_b[0], bb1 = Win_b[1], bb2 = Win_b[2], bb3 = Win_b[3];

  const int r0 = blockIdx.x * rowsPerBlk;
  float2 xv = *reinterpret_cast<const float2*>(x + (size_t)r0 * FF + 2*lane);
  for (int k = 0; k < rowsPerBlk; ++k) {
    const int r = r0 + k;
    float2 cur = xv;
    if (k + 1 < rowsPerBlk)
      xv = *reinterpret_cast<const float2*>(x + (size_t)(r + 1) * FF + 2*lane);
    float p0 = fmaf(cur.x, wx0a, cur.y * wx0b);
    float p1 = fmaf(cur.x, wx1a, cur.y * wx1b);
    float p2 = fmaf(cur.x, wx2a, cur.y * wx2b);
    float p3 = fmaf(cur.x, wx3a, cur.y * wx3b);
    p0 = red64(p0); p1 = red64(p1); p2 = red64(p2); p3 = red64(p3);
    if (lane == 0)
      reinterpret_cast<float4*>(yx)[r] = make_float4(p0 + bb0, p1 + bb1, p2 + bb2, p3 + bb3);
  }
}

// ============================================================
// Kernel 2: recurrent scan — ONE chain per wave, 2 units/lane.
// R4's minimal arithmetic, now 4-step-unrolled with 2 alternating
// prefetch banks so VMEM register reuse distance >> store/load latency
// (no per-step s_waitcnt on the streaming h-store or yx prefetch).
// ============================================================
__global__ __launch_bounds__(64)
void qlstm_rec(const float* __restrict__ Win_w,
               const float* __restrict__ Wout_w,
               const float* __restrict__ Wout_b,
               const float* __restrict__ w_f,
               const float* __restrict__ w_i,
               const float* __restrict__ w_u,
               const float* __restrict__ w_o,
               const float* __restrict__ yx,
               float* __restrict__ out)
{
  const int lane = threadIdx.x;
  const int b    = blockIdx.x;
  const int j0   = 2*lane, j1 = 2*lane + 1;

  constexpr float L2E  = 1.4426950408889634f;
  constexpr float NL2E = -L2E;          // sigmoid prescale (f,i,o)
  constexpr float T2E  = 2.0f * L2E;    // tanh prescale (u, and tanh(c))

  // recurrent weights Wh[q][j0], Wh[q][j1]
  float whA[4], whB[4];
  #pragma unroll
  for (int q = 0; q < 4; ++q) {
    whA[q] = Win_w[q*256 + j0];
    whB[q] = Win_w[q*256 + j1];
  }

  // z weight packs per unit: fi-pair shares NL2E on both halves;
  // uo-pair = {T2E (u), NL2E (o)}.  Hoisted: no in-loop broadcasts.
  const float4 r0v = reinterpret_cast<const float4*>(Wout_w)[j0];
  const float4 r1v = reinterpret_cast<const float4*>(Wout_w)[j1];
  const float w0[4] = {r0v.x, r0v.y, r0v.z, r0v.w};
  const float w1[4] = {r1v.x, r1v.y, r1v.z, r1v.w};
  f2 wfi0[4], wfi1[4], wuo0[4], wuo1[4];
  #pragma unroll
  for (int k = 0; k < 4; ++k) {
    wfi0[k] = (f2){ w0[k]*NL2E, w0[k]*NL2E };
    wfi1[k] = (f2){ w1[k]*NL2E, w1[k]*NL2E };
    wuo0[k] = (f2){ w0[k]*T2E,  w0[k]*NL2E };
    wuo1[k] = (f2){ w1[k]*T2E,  w1[k]*NL2E };
  }
  const float b0s = Wout_b[j0], b1s = Wout_b[j1];
  const f2 bfi0 = (f2){ b0s*NL2E, b0s*NL2E };
  const f2 bfi1 = (f2){ b1s*NL2E, b1s*NL2E };
  const f2 buo0 = (f2){ b0s*T2E,  b0s*NL2E };
  const f2 buo1 = (f2){ b1s*T2E,  b1s*NL2E };

  // ring RY coefficients packed across gate pairs (f,i) and (u,o)
  f2 cwfi[4], swfi[4], cwuo[4], swuo[4];
  #pragma unroll
  for (int q = 0; q < 4; ++q) {
    cwfi[q] = (f2){ -cosf(w_f[q]), -cosf(w_i[q]) };
    swfi[q] = (f2){ -sinf(w_f[q]), -sinf(w_i[q]) };
    cwuo[q] = (f2){ -cosf(w_u[q]), -cosf(w_o[q]) };
    swuo[q] = (f2){ -sinf(w_u[q]), -sinf(w_o[q]) };
  }

  float h0 = 0.f, h1 = 0.f, c0 = 0.f, c1 = 0.f;

  const float4* yxb = reinterpret_cast<const float4*>(yx) + (size_t)b * TT;
  float* outp = out + (size_t)b * TT * HH + j0;   // walks forward by HH

  // one full LSTM step from staged y-vector yc; stores h via distinct temp
  auto STEP = [&](const float4 yc, float* op) {
    // ---- y = Wh @ h + y_x  (DPP + permlane allreduce over 64 lanes) ----
    float s0 = fmaf(h0, whA[0], h1 * whB[0]);
    float s1 = fmaf(h0, whA[1], h1 * whB[1]);
    float s2 = fmaf(h0, whA[2], h1 * whB[2]);
    float s3 = fmaf(h0, whA[3], h1 * whB[3]);
    s0 = red64(s0); s1 = red64(s1); s2 = red64(s2); s3 = red64(s3);

    // ---- per-qubit A = y*r, B = r*rr (packed over qubit pairs) ----
    const f2 y01 = (f2){ s0 + yc.x, s1 + yc.y };
    const f2 y23 = (f2){ s2 + yc.z, s3 + yc.w };
    const f2 y2a = y01 * y01, y2b = y23 * y23;
    const f2 p1a = y2a + 1.f, p1b = y2b + 1.f;
    const f2 p2a = pkfma(y2a, y2a, splat(1.f));
    const f2 p2b = pkfma(y2b, y2b, splat(1.f));
    const f2 rA  = (f2){ rsq_f(p1a.x), rsq_f(p1a.y) };
    const f2 rB  = (f2){ rsq_f(p1b.x), rsq_f(p1b.y) };
    const f2 rrA = (f2){ rsq_f(p2a.x), rsq_f(p2a.y) };
    const f2 rrB = (f2){ rsq_f(p2b.x), rsq_f(p2b.y) };
    const f2 A01 = y01 * rA, A23 = y23 * rB;
    const f2 B01 = rA * rrA, B23 = rB * rrB;

    const f2 bA0 = splat(A01.x), bA1 = splat(A01.y);
    const f2 bA2 = splat(A23.x), bA3 = splat(A23.y);
    const f2 bB0 = splat(B01.x), bB1 = splat(B01.y);
    const f2 bB2 = splat(B23.x), bB3 = splat(B23.y);

    // ---- d packs per gate pair, E products ----
    const f2 d0fi = pkfma(cwfi[0], bA0, swfi[0] * bB0);
    const f2 d1fi = pkfma(cwfi[1], bA1, swfi[1] * bB1);
    const f2 d2fi = pkfma(cwfi[2], bA2, swfi[2] * bB2);
    const f2 d3fi = pkfma(cwfi[3], bA3, swfi[3] * bB3);
    const f2 d0uo = pkfma(cwuo[0], bA0, swuo[0] * bB0);
    const f2 d1uo = pkfma(cwuo[1], bA1, swuo[1] * bB1);
    const f2 d2uo = pkfma(cwuo[2], bA2, swuo[2] * bB2);
    const f2 d3uo = pkfma(cwuo[3], bA3, swuo[3] * bB3);

    const f2 e1fi = d0fi * d1fi, dpfi = d2fi * d3fi;
    const f2 e0fi = d1fi * dpfi, e2fi = e1fi * d2fi, e3fi = e1fi * dpfi;
    const f2 e1uo = d0uo * d1uo, dpuo = d2uo * d3uo;
    const f2 e0uo = d1uo * dpuo, e2uo = e1uo * d2uo, e3uo = e1uo * dpuo;

    // ---- z packs {zf,zi} and {zu,zo} per unit ----
    const f2 zfi0 = pkfma(e0fi, wfi0[0], pkfma(e1fi, wfi0[1],
                    pkfma(e2fi, wfi0[2], pkfma(e3fi, wfi0[3], bfi0))));
    const f2 zfi1 = pkfma(e0fi, wfi1[0], pkfma(e1fi, wfi1[1],
                    pkfma(e2fi, wfi1[2], pkfma(e3fi, wfi1[3], bfi1))));
    const f2 zuo0 = pkfma(e0uo, wuo0[0], pkfma(e1uo, wuo0[1],
                    pkfma(e2uo, wuo0[2], pkfma(e3uo, wuo0[3], buo0))));
    const f2 zuo1 = pkfma(e0uo, wuo1[0], pkfma(e1uo, wuo1[1],
                    pkfma(e2uo, wuo1[2], pkfma(e3uo, wuo1[3], buo1))));

    // ---- activations: exfi = {a, b}, exuo = {u, d} ----
    const f2 exfi0 = ex2_2(zfi0), exfi1 = ex2_2(zfi1);
    const f2 exuo0 = ex2_2(zuo0), exuo1 = ex2_2(zuo1);
    const f2 pfi0 = exfi0 + 1.f, pfi1 = exfi1 + 1.f;   // {1+a, 1+b}
    const f2 puo0 = exuo0 + 1.f, puo1 = exuo1 + 1.f;   // {1+u, 1+d}
    const float um0 = exuo0.x - 1.f, um1 = exuo1.x - 1.f;

    // ---- fused c update ----
    {
      const float t1 = pfi0.y * puo0.x;
      const float num = fmaf(c0, t1, pfi0.x * um0);
      c0 = num * rcp_f(pfi0.x * t1);
    }
    {
      const float t1 = pfi1.y * puo1.x;
      const float num = fmaf(c1, t1, pfi1.x * um1);
      c1 = num * rcp_f(pfi1.x * t1);
    }

    // ---- h = (v-1)/((1+d)(v+1)), v = exp2(T2E*c') ----
    {
      const float v = ex2_f(c0 * T2E);
      h0 = (v - 1.f) * rcp_f(puo0.y * (v + 1.f));
    }
    {
      const float v = ex2_f(c1 * T2E);
      h1 = (v - 1.f) * rcp_f(puo1.y * (v + 1.f));
    }

    const float2 hv = make_float2(h0, h1);   // distinct temp per call site
    *reinterpret_cast<float2*>(op) = hv;
  };

  constexpr int NG = TT / 4;   // 128 groups of 4 steps

  // bank A = group 0, bank B = group 1 (preloaded)
  float4 ya0 = yxb[0], ya1 = yxb[1], ya2 = yxb[2], ya3 = yxb[3];
  float4 yb0 = yxb[4], yb1 = yxb[5], yb2 = yxb[6], yb3 = yxb[7];

  for (int g = 0; g < NG; g += 2) {
    // consume bank A (group g)
    STEP(ya0, outp);            outp += HH;
    STEP(ya1, outp);            outp += HH;
    STEP(ya2, outp);            outp += HH;
    STEP(ya3, outp);            outp += HH;
    // refill bank A with group g+2 (clamped)
    {
      const int n = ((g + 2 < NG) ? g + 2 : NG - 1) * 4;
      ya0 = yxb[n]; ya1 = yxb[n+1]; ya2 = yxb[n+2]; ya3 = yxb[n+3];
    }
    // consume bank B (group g+1)
    STEP(yb0, outp);            outp += HH;
    STEP(yb1, outp);            outp += HH;
    STEP(yb2, outp);            outp += HH;
    STEP(yb3, outp);            outp += HH;
    // refill bank B with group g+3 (clamped)
    {
      const int n = ((g + 3 < NG) ? g + 3 : NG - 1) * 4;
      yb0 = yxb[n]; yb1 = yxb[n+1]; yb2 = yxb[n+2]; yb3 = yxb[n+3];
    }
  }

  const size_t hoff = (size_t)BB * TT * HH;
  *reinterpret_cast<float2*>(out + hoff + (size_t)b * HH + j0) = make_float2(h0, h1);
  const size_t coff = hoff + (size_t)BB * HH;
  *reinterpret_cast<float2*>(out + coff + (size_t)b * HH + j0) = make_float2(c0, c1);
}

extern "C" void kernel_launch(void* const* d_in, const int* in_sizes, int n_in,
                              void* d_out, int out_size, void* d_ws, size_t ws_size,
                              hipStream_t stream) {
  const float* x      = (const float*)d_in[0];
  const float* Win_w  = (const float*)d_in[1];
  const float* Win_b  = (const float*)d_in[2];
  const float* Wout_w = (const float*)d_in[3];
  const float* Wout_b = (const float*)d_in[4];
  const float* w_f    = (const float*)d_in[5];
  const float* w_i    = (const float*)d_in[6];
  const float* w_u    = (const float*)d_in[7];
  const float* w_o    = (const float*)d_in[8];
  float* out = (float*)d_out;
  float* yx  = (float*)d_ws;   // B*T*4 floats = 2 MB scratch

  const int rows = BB * TT;          // 131072
  const int rowsPerBlk = 16;
  yx_pre<<<rows / rowsPerBlk, 64, 0, stream>>>(x, Win_w, Win_b, yx, rowsPerBlk);
  qlstm_rec<<<BB, 64, 0, stream>>>(Win_w, Wout_w, Wout_b, w_f, w_i, w_u, w_o, yx, out);
}